// Round 1
// baseline (755.076 us; speedup 1.0000x reference)
//
#include <hip/hip_runtime.h>
#include <cstdint>
#include <cstddef>

// HyenaCascade on MI355X — 3-phase chunked bidirectional 16-state scan.
// R2: CH=32 + 4-wave workgroups (8192 waves -> 32 waves/CU, was grid-limited
//     to 16), packed f32x2 FIR + packed residue reduction, guard-free interior
//     chunks. PhaseB batched depth 32.

#define Bn 2
#define Ln 8192
#define HIDn 1024
#define HEADSn 16
#define STATEn 16
#define THIDn 3072  // 3*HID

typedef __attribute__((ext_vector_type(2))) float f32x2;
typedef __attribute__((ext_vector_type(4))) float f32x4;

// load u[b, t, c] given base = &u[b,0,c]; zero outside [0,L) when G
template <bool G>
__device__ __forceinline__ float ldc(const float* __restrict__ base, int t) {
    if constexpr (G) return ((unsigned)t < (unsigned)Ln) ? base[(size_t)t * THIDn] : 0.0f;
    else return base[(size_t)t * THIDn];
}

// ---------------- Phase A: per-chunk local scan finals ----------------
template <int CH, bool G>
__device__ __forceinline__ void phaseA_body(
    const float* __restrict__ u1, const float* __restrict__ uv,
    const f32x2 W0, const f32x2 W1, const f32x2 W2,
    const f32x2 (&p2)[8], int t0,
    float* __restrict__ cF, float* __restrict__ cG) {
    const int t1 = t0 + CH - 1;
    // ---- forward local scan ----
    {
        f32x2 f2[8];
#pragma unroll
        for (int s = 0; s < 8; ++s) f2[s] = (f32x2){0.0f, 0.0f};
        f32x2 av0 = {ldc<G>(u1, t0 - 2), ldc<G>(uv, t0 - 2)};
        f32x2 av1 = {ldc<G>(u1, t0 - 1), ldc<G>(uv, t0 - 1)};
        f32x2 av2 = {ldc<G>(u1, t0    ), ldc<G>(uv, t0    )};
        f32x2 av3 = {ldc<G>(u1, t0 + 1), ldc<G>(uv, t0 + 1)};
#pragma unroll 8
        for (int tt = 0; tt < CH; ++tt) {
            const int t = t0 + tt;
            const f32x2 av4 = {ldc<G>(u1, t + 2), ldc<G>(uv, t + 2)};
            const f32x2 z = __builtin_elementwise_fma(W0, av0 + av4,
                              __builtin_elementwise_fma(W1, av1 + av3, W2 * av2));
            const float x = z.x * z.y;
            const f32x2 xb = {x, x};
#pragma unroll
            for (int s = 0; s < 8; ++s) f2[s] = __builtin_elementwise_fma(p2[s], f2[s], xb);
            av0 = av1; av1 = av2; av2 = av3; av3 = av4;
        }
        f32x4* o = (f32x4*)cF;
#pragma unroll
        for (int s = 0; s < 4; ++s)
            o[s] = (f32x4){f2[2 * s].x, f2[2 * s].y, f2[2 * s + 1].x, f2[2 * s + 1].y};
    }
    // ---- backward local scan (recompute x1v; chunk data is L1/L2-hot) ----
    {
        f32x2 g2[8];
#pragma unroll
        for (int s = 0; s < 8; ++s) g2[s] = (f32x2){0.0f, 0.0f};
        f32x2 av4 = {ldc<G>(u1, t1 + 2), ldc<G>(uv, t1 + 2)};
        f32x2 av3 = {ldc<G>(u1, t1 + 1), ldc<G>(uv, t1 + 1)};
        f32x2 av2 = {ldc<G>(u1, t1    ), ldc<G>(uv, t1    )};
        f32x2 av1 = {ldc<G>(u1, t1 - 1), ldc<G>(uv, t1 - 1)};
#pragma unroll 8
        for (int tt = CH - 1; tt >= 0; --tt) {
            const int t = t0 + tt;
            const f32x2 av0 = {ldc<G>(u1, t - 2), ldc<G>(uv, t - 2)};
            const f32x2 z = __builtin_elementwise_fma(W0, av0 + av4,
                              __builtin_elementwise_fma(W1, av1 + av3, W2 * av2));
            const float x = z.x * z.y;
            const f32x2 xb = {x, x};
#pragma unroll
            for (int s = 0; s < 8; ++s) g2[s] = __builtin_elementwise_fma(p2[s], g2[s], xb);
            av4 = av3; av3 = av2; av2 = av1; av1 = av0;
        }
        f32x4* o = (f32x4*)cG;
#pragma unroll
        for (int s = 0; s < 4; ++s)
            o[s] = (f32x4){g2[2 * s].x, g2[2 * s].y, g2[2 * s + 1].x, g2[2 * s + 1].y};
    }
}

template <int CH>
__global__ __launch_bounds__(256, 8) void hyena_phaseA(
    const float* __restrict__ u, const float* __restrict__ sfw,
    const float* __restrict__ lp,
    float* __restrict__ carryF, float* __restrict__ carryG) {
    constexpr int NC = Ln / CH;
    const int lane = threadIdx.x & 63;
    const int chunk = (blockIdx.x << 2) + (threadIdx.x >> 6);  // 4 chunks/block
    const int h = blockIdx.y;
    const int b = blockIdx.z;
    const int c1 = h * 192 + 64 + lane;  // x1 column in u
    const int cv = c1 + 64;              // v column
    const int t0 = chunk * CH;

    const float* u1 = u + (size_t)b * Ln * THIDn + c1;
    const float* uv = u + (size_t)b * Ln * THIDn + cv;
    const f32x2 W0 = {sfw[c1 * 3 + 0], sfw[cv * 3 + 0]};
    const f32x2 W1 = {sfw[c1 * 3 + 1], sfw[cv * 3 + 1]};
    const f32x2 W2 = {2.0f * sfw[c1 * 3 + 2], 2.0f * sfw[cv * 3 + 2]};
    f32x2 p2[8];
#pragma unroll
    for (int s = 0; s < 8; ++s) p2[s] = (f32x2){expf(lp[2 * s]), expf(lp[2 * s + 1])};

    const int gch = b * HIDn + h * 64 + lane;
    const size_t cbase = ((size_t)chunk * (Bn * HIDn) + gch) * 16;  // chunk-major

    if (chunk >= 1 && chunk <= NC - 2)
        phaseA_body<CH, false>(u1, uv, W0, W1, W2, p2, t0, carryF + cbase, carryG + cbase);
    else
        phaseA_body<CH, true>(u1, uv, W0, W1, W2, p2, t0, carryF + cbase, carryG + cbase);
}

// ---------------- Phase B: carry combine across chunks (in-place) ----------------
template <int CH>
__global__ __launch_bounds__(256) void hyena_phaseB(
    const float* __restrict__ lp,
    float* __restrict__ carryF, float* __restrict__ carryG) {
    constexpr int NC = Ln / CH;
    constexpr int UB = (NC >= 32) ? 32 : 16;  // batched loads (NC % UB == 0)
    const int dir = blockIdx.x >> 7;                          // blocks 0..127 fwd, 128..255 bwd
    const int ht = ((blockIdx.x & 127) << 8) + threadIdx.x;   // 0..32767
    const int s = ht & 15;
    const int gch = ht >> 4;                                  // 0..2047
    const float pCH = expf(lp[s] * (float)CH);
    float c = 0.0f;
    if (dir == 0) {
        for (int k0 = 0; k0 < NC; k0 += UB) {
            float loc[UB];
#pragma unroll
            for (int q = 0; q < UB; ++q)
                loc[q] = carryF[((size_t)(k0 + q) * (Bn * HIDn) + gch) * 16 + s];
#pragma unroll
            for (int q = 0; q < UB; ++q) {
                carryF[((size_t)(k0 + q) * (Bn * HIDn) + gch) * 16 + s] = c;
                c = fmaf(pCH, c, loc[q]);
            }
        }
    } else {
        for (int k0 = NC - UB; k0 >= 0; k0 -= UB) {
            float loc[UB];
#pragma unroll
            for (int q = UB - 1; q >= 0; --q)
                loc[q] = carryG[((size_t)(k0 + q) * (Bn * HIDn) + gch) * 16 + s];
#pragma unroll
            for (int q = UB - 1; q >= 0; --q) {
                carryG[((size_t)(k0 + q) * (Bn * HIDn) + gch) * 16 + s] = c;
                c = fmaf(pCH, c, loc[q]);
            }
        }
    }
}

// ---------------- Phase C: seeded scans + gating + output ----------------
// fwd pass writes causal y_c to out; bwd pass does same-thread RMW:
// out = (y_c + y_a + D*x) * x2. All addresses lane-private -> no sync needed.
template <int CH, bool G>
__device__ __forceinline__ void phaseC_body(
    const float* __restrict__ u2, const float* __restrict__ u1, const float* __restrict__ uv,
    float* __restrict__ op,
    const f32x2 W0, const f32x2 W1, const f32x2 W2,
    const float w20, const float w21, const float w22,
    const f32x2 (&p2)[8], const f32x2 (&rr2)[8], const float dI,
    const float* __restrict__ cF, const float* __restrict__ cG, int t0) {
    const int t1 = t0 + CH - 1;
    // ---- forward pass: causal branch, y_c -> out ----
    {
        f32x2 f2[8];
        const f32x4* ci = (const f32x4*)cF;
#pragma unroll
        for (int s = 0; s < 4; ++s) {
            const f32x4 q = ci[s];
            f2[2 * s]     = (f32x2){q.x, q.y};
            f2[2 * s + 1] = (f32x2){q.z, q.w};
        }
        f32x2 av0 = {ldc<G>(u1, t0 - 2), ldc<G>(uv, t0 - 2)};
        f32x2 av1 = {ldc<G>(u1, t0 - 1), ldc<G>(uv, t0 - 1)};
        f32x2 av2 = {ldc<G>(u1, t0    ), ldc<G>(uv, t0    )};
        f32x2 av3 = {ldc<G>(u1, t0 + 1), ldc<G>(uv, t0 + 1)};
#pragma unroll 8
        for (int tt = 0; tt < CH; ++tt) {
            const int t = t0 + tt;
            const f32x2 av4 = {ldc<G>(u1, t + 2), ldc<G>(uv, t + 2)};
            const f32x2 z = __builtin_elementwise_fma(W0, av0 + av4,
                              __builtin_elementwise_fma(W1, av1 + av3, W2 * av2));
            const float x = z.x * z.y;
            const f32x2 xb = {x, x};
#pragma unroll
            for (int s = 0; s < 8; ++s) f2[s] = __builtin_elementwise_fma(p2[s], f2[s], xb);
            f32x2 accA = rr2[0] * f2[0];
            f32x2 accB = rr2[1] * f2[1];
#pragma unroll
            for (int s = 2; s < 8; s += 2) {
                accA = __builtin_elementwise_fma(rr2[s], f2[s], accA);
                accB = __builtin_elementwise_fma(rr2[s + 1], f2[s + 1], accB);
            }
            const f32x2 acc = accA + accB;
            op[(size_t)t * HIDn] = acc.x + acc.y;
            av0 = av1; av1 = av2; av2 = av3; av3 = av4;
        }
    }
    // ---- backward pass: anti-causal branch + skip + gate, RMW out ----
    {
        f32x2 g2[8];
        const f32x4* ci = (const f32x4*)cG;
#pragma unroll
        for (int s = 0; s < 4; ++s) {
            const f32x4 q = ci[s];
            g2[2 * s]     = (f32x2){q.x, q.y};
            g2[2 * s + 1] = (f32x2){q.z, q.w};
        }
        f32x2 av4 = {ldc<G>(u1, t1 + 2), ldc<G>(uv, t1 + 2)};
        f32x2 av3 = {ldc<G>(u1, t1 + 1), ldc<G>(uv, t1 + 1)};
        f32x2 av2 = {ldc<G>(u1, t1    ), ldc<G>(uv, t1    )};
        f32x2 av1 = {ldc<G>(u1, t1 - 1), ldc<G>(uv, t1 - 1)};
        float e4 = ldc<G>(u2, t1 + 2), e3 = ldc<G>(u2, t1 + 1);
        float e2 = ldc<G>(u2, t1), e1 = ldc<G>(u2, t1 - 1);
#pragma unroll 8
        for (int tt = CH - 1; tt >= 0; --tt) {
            const int t = t0 + tt;
            const float yc = op[(size_t)t * HIDn];  // own earlier store; L2-hot
            const f32x2 av0 = {ldc<G>(u1, t - 2), ldc<G>(uv, t - 2)};
            const float e0 = ldc<G>(u2, t - 2);
            const f32x2 z = __builtin_elementwise_fma(W0, av0 + av4,
                              __builtin_elementwise_fma(W1, av1 + av3, W2 * av2));
            const float z2 = fmaf(w20, e0 + e4, fmaf(w21, e1 + e3, w22 * e2));
            const float x = z.x * z.y;
            const f32x2 xb = {x, x};
#pragma unroll
            for (int s = 0; s < 8; ++s) g2[s] = __builtin_elementwise_fma(p2[s], g2[s], xb);
            f32x2 accA = rr2[0] * g2[0];
            f32x2 accB = rr2[1] * g2[1];
#pragma unroll
            for (int s = 2; s < 8; s += 2) {
                accA = __builtin_elementwise_fma(rr2[s], g2[s], accA);
                accB = __builtin_elementwise_fma(rr2[s + 1], g2[s + 1], accB);
            }
            const f32x2 acc = accA + accB;
            const float ya = acc.x + acc.y;
            op[(size_t)t * HIDn] = (yc + ya + dI * x) * z2;
            av4 = av3; av3 = av2; av2 = av1; av1 = av0;
            e4 = e3; e3 = e2; e2 = e1; e1 = e0;
        }
    }
}

template <int CH>
__global__ __launch_bounds__(256, 8) void hyena_phaseC(
    const float* __restrict__ u, const float* __restrict__ sfw,
    const float* __restrict__ lp, const float* __restrict__ res,
    const float* __restrict__ Dp,
    const float* __restrict__ carryF, const float* __restrict__ carryG,
    float* __restrict__ out) {
    constexpr int NC = Ln / CH;
    const int lane = threadIdx.x & 63;
    const int chunk = (blockIdx.x << 2) + (threadIdx.x >> 6);  // 4 chunks/block
    const int h = blockIdx.y;
    const int b = blockIdx.z;
    const int c2 = h * 192 + lane;    // x2 (gate) column
    const int c1 = c2 + 64;           // x1 column
    const int cv = c2 + 128;          // v column
    const int i = h * 64 + lane;
    const int gch = b * HIDn + i;
    const int t0 = chunk * CH;

    const float* u2 = u + (size_t)b * Ln * THIDn + c2;
    const float* u1 = u + (size_t)b * Ln * THIDn + c1;
    const float* uv = u + (size_t)b * Ln * THIDn + cv;
    float* op = out + (size_t)b * Ln * HIDn + i;
    const float w20 = sfw[c2 * 3 + 0], w21 = sfw[c2 * 3 + 1], w22 = 2.0f * sfw[c2 * 3 + 2];
    const f32x2 W0 = {sfw[c1 * 3 + 0], sfw[cv * 3 + 0]};
    const f32x2 W1 = {sfw[c1 * 3 + 1], sfw[cv * 3 + 1]};
    const f32x2 W2 = {2.0f * sfw[c1 * 3 + 2], 2.0f * sfw[cv * 3 + 2]};

    f32x2 p2[8], rr2[8];
#pragma unroll
    for (int s = 0; s < 8; ++s) {
        p2[s]  = (f32x2){expf(lp[2 * s]), expf(lp[2 * s + 1])};
        rr2[s] = (f32x2){res[2 * s], res[2 * s + 1]};  // uniform -> s_load
    }
    const float dI = Dp[i];
    const size_t cbase = ((size_t)chunk * (Bn * HIDn) + gch) * 16;

    if (chunk >= 1 && chunk <= NC - 2)
        phaseC_body<CH, false>(u2, u1, uv, op, W0, W1, W2, w20, w21, w22,
                               p2, rr2, dI, carryF + cbase, carryG + cbase, t0);
    else
        phaseC_body<CH, true>(u2, u1, uv, op, W0, W1, W2, w20, w21, w22,
                              p2, rr2, dI, carryF + cbase, carryG + cbase, t0);
}

template <int CH>
static void run_all(const float* u, const float* sfw, const float* lp,
                    const float* res, const float* Dp, float* out,
                    void* ws, hipStream_t stream) {
    constexpr int NC = Ln / CH;
    static_assert(NC % 4 == 0, "4 chunks per block");
    float* carryF = (float*)ws;
    float* carryG = carryF + (size_t)NC * (Bn * HIDn) * 16;
    dim3 grid(NC / 4, HEADSn, Bn);
    hipLaunchKernelGGL((hyena_phaseA<CH>), grid, dim3(256), 0, stream,
                       u, sfw, lp, carryF, carryG);
    hipLaunchKernelGGL((hyena_phaseB<CH>), dim3(256), dim3(256), 0, stream,
                       lp, carryF, carryG);
    hipLaunchKernelGGL((hyena_phaseC<CH>), grid, dim3(256), 0, stream,
                       u, sfw, lp, res, Dp, carryF, carryG, out);
}

extern "C" void kernel_launch(void* const* d_in, const int* in_sizes, int n_in,
                              void* d_out, int out_size, void* d_ws, size_t ws_size,
                              hipStream_t stream) {
    const float* u   = (const float*)d_in[0];  // (B, L, 3*HID) fp32
    const float* sfw = (const float*)d_in[1];  // (3*HID, 1, 3)
    const float* lp  = (const float*)d_in[2];  // (1, 16, 1)
    const float* res = (const float*)d_in[3];  // (1, 16)
    const float* Dp  = (const float*)d_in[4];  // (HID,)
    float* out = (float*)d_out;                // (B, L, HID) fp32

    // carry workspace: NC * 2048 channels * 32 states * 4 B = 2^31/CH bytes
    const size_t need32 = ((size_t)1 << 31) / 32;  // 64 MiB at CH=32
    if (ws_size >= need32)            run_all<32>(u, sfw, lp, res, Dp, out, d_ws, stream);
    else if (ws_size >= need32 / 2)   run_all<64>(u, sfw, lp, res, Dp, out, d_ws, stream);
    else if (ws_size >= need32 / 4)   run_all<128>(u, sfw, lp, res, Dp, out, d_ws, stream);
    else if (ws_size >= need32 / 8)   run_all<256>(u, sfw, lp, res, Dp, out, d_ws, stream);
    else                              run_all<512>(u, sfw, lp, res, Dp, out, d_ws, stream);
}

// Round 2
// 658.523 us; speedup vs baseline: 1.1466x; 1.1466x over previous
//
#include <hip/hip_runtime.h>
#include <cstdint>
#include <cstddef>

// HyenaCascade on MI355X — 3-phase chunked bidirectional 16-state scan.
// R3: revert to R1 launch geometry (CH=64, 1-wave WGs — R2's 2x occupancy
//     blew the L3 reuse window: FETCH 217->724 MB, 3x regression).
//     New: phaseA computes BOTH direction finals in ONE sweep (running-weight
//     trick g = sum p^tt x);  phaseC keeps ya in a full-unrolled register
//     array -> single out store, no RMW, no yc re-read. Packed f32x2 FIR.

#define Bn 2
#define Ln 8192
#define HIDn 1024
#define HEADSn 16
#define STATEn 16
#define THIDn 3072  // 3*HID

typedef __attribute__((ext_vector_type(2))) float f32x2;
typedef __attribute__((ext_vector_type(4))) float f32x4;

// load u[b, t, c] given base = &u[b,0,c]; zero outside [0,L) when G
template <bool G>
__device__ __forceinline__ float ldc(const float* __restrict__ base, int t) {
    if constexpr (G) return ((unsigned)t < (unsigned)Ln) ? base[(size_t)t * THIDn] : 0.0f;
    else return base[(size_t)t * THIDn];
}

// ---------------- Phase A: per-chunk local finals, ONE sweep ----------------
// fwd final: f = p*f + x (t0..t1).  bwd final: g(t0) = sum_tt p^tt x(t0+tt)
// computed forward with running weight wq *= p. Halves loads vs 2-sweep.
template <int CH, bool G>
__device__ __forceinline__ void phaseA_body(
    const float* __restrict__ u1, const float* __restrict__ uv,
    const f32x2 W0, const f32x2 W1, const f32x2 W2,
    const f32x2 (&p2)[8], int t0,
    float* __restrict__ cF, float* __restrict__ cG) {
    f32x2 f2[8], g2[8], wq[8];
#pragma unroll
    for (int s = 0; s < 8; ++s) {
        f2[s] = (f32x2){0.0f, 0.0f};
        g2[s] = (f32x2){0.0f, 0.0f};
        wq[s] = (f32x2){1.0f, 1.0f};
    }
    f32x2 av0 = {ldc<G>(u1, t0 - 2), ldc<G>(uv, t0 - 2)};
    f32x2 av1 = {ldc<G>(u1, t0 - 1), ldc<G>(uv, t0 - 1)};
    f32x2 av2 = {ldc<G>(u1, t0    ), ldc<G>(uv, t0    )};
    f32x2 av3 = {ldc<G>(u1, t0 + 1), ldc<G>(uv, t0 + 1)};
#pragma unroll 8
    for (int tt = 0; tt < CH; ++tt) {
        const int t = t0 + tt;
        const f32x2 av4 = {ldc<G>(u1, t + 2), ldc<G>(uv, t + 2)};
        const f32x2 z = __builtin_elementwise_fma(W0, av0 + av4,
                          __builtin_elementwise_fma(W1, av1 + av3, W2 * av2));
        const float x = z.x * z.y;
        const f32x2 xb = {x, x};
#pragma unroll
        for (int s = 0; s < 8; ++s) {
            f2[s] = __builtin_elementwise_fma(p2[s], f2[s], xb);
            g2[s] = __builtin_elementwise_fma(wq[s], xb, g2[s]);
            wq[s] = wq[s] * p2[s];
        }
        av0 = av1; av1 = av2; av2 = av3; av3 = av4;
    }
    f32x4* oF = (f32x4*)cF;
    f32x4* oG = (f32x4*)cG;
#pragma unroll
    for (int s = 0; s < 4; ++s) {
        oF[s] = (f32x4){f2[2 * s].x, f2[2 * s].y, f2[2 * s + 1].x, f2[2 * s + 1].y};
        oG[s] = (f32x4){g2[2 * s].x, g2[2 * s].y, g2[2 * s + 1].x, g2[2 * s + 1].y};
    }
}

template <int CH>
__global__ __launch_bounds__(64, 4) void hyena_phaseA(
    const float* __restrict__ u, const float* __restrict__ sfw,
    const float* __restrict__ lp,
    float* __restrict__ carryF, float* __restrict__ carryG) {
    constexpr int NC = Ln / CH;
    const int j = threadIdx.x;        // channel within head
    const int chunk = blockIdx.x;
    const int h = blockIdx.y;
    const int b = blockIdx.z;
    const int c1 = h * 192 + 64 + j;  // x1 column in u
    const int cv = c1 + 64;           // v column
    const int t0 = chunk * CH;

    const float* u1 = u + (size_t)b * Ln * THIDn + c1;
    const float* uv = u + (size_t)b * Ln * THIDn + cv;
    const f32x2 W0 = {sfw[c1 * 3 + 0], sfw[cv * 3 + 0]};
    const f32x2 W1 = {sfw[c1 * 3 + 1], sfw[cv * 3 + 1]};
    const f32x2 W2 = {2.0f * sfw[c1 * 3 + 2], 2.0f * sfw[cv * 3 + 2]};
    f32x2 p2[8];
#pragma unroll
    for (int s = 0; s < 8; ++s) p2[s] = (f32x2){expf(lp[2 * s]), expf(lp[2 * s + 1])};

    const int gch = b * HIDn + h * 64 + j;
    const size_t cbase = ((size_t)chunk * (Bn * HIDn) + gch) * 16;  // chunk-major

    if (chunk >= 1 && chunk <= NC - 2)
        phaseA_body<CH, false>(u1, uv, W0, W1, W2, p2, t0, carryF + cbase, carryG + cbase);
    else
        phaseA_body<CH, true>(u1, uv, W0, W1, W2, p2, t0, carryF + cbase, carryG + cbase);
}

// ---------------- Phase B: carry combine across chunks (in-place) ----------------
template <int CH>
__global__ __launch_bounds__(256) void hyena_phaseB(
    const float* __restrict__ lp,
    float* __restrict__ carryF, float* __restrict__ carryG) {
    constexpr int NC = Ln / CH;
    constexpr int UB = 16;  // batched loads (NC % UB == 0 for all CH used)
    const int dir = blockIdx.x >> 7;                          // blocks 0..127 fwd, 128..255 bwd
    const int ht = ((blockIdx.x & 127) << 8) + threadIdx.x;   // 0..32767
    const int s = ht & 15;
    const int gch = ht >> 4;                                  // 0..2047
    const float pCH = expf(lp[s] * (float)CH);
    float c = 0.0f;
    if (dir == 0) {
        for (int k0 = 0; k0 < NC; k0 += UB) {
            float loc[UB];
#pragma unroll
            for (int q = 0; q < UB; ++q)
                loc[q] = carryF[((size_t)(k0 + q) * (Bn * HIDn) + gch) * 16 + s];
#pragma unroll
            for (int q = 0; q < UB; ++q) {
                carryF[((size_t)(k0 + q) * (Bn * HIDn) + gch) * 16 + s] = c;
                c = fmaf(pCH, c, loc[q]);
            }
        }
    } else {
        for (int k0 = NC - UB; k0 >= 0; k0 -= UB) {
            float loc[UB];
#pragma unroll
            for (int q = UB - 1; q >= 0; --q)
                loc[q] = carryG[((size_t)(k0 + q) * (Bn * HIDn) + gch) * 16 + s];
#pragma unroll
            for (int q = UB - 1; q >= 0; --q) {
                carryG[((size_t)(k0 + q) * (Bn * HIDn) + gch) * 16 + s] = c;
                c = fmaf(pCH, c, loc[q]);
            }
        }
    }
}

// ---------------- Phase C: seeded scans + gating + SINGLE output store ----------
// sweep 1 (bwd): ya[tt] = y_a(t) + D*x(t) kept in registers (full unroll).
// sweep 2 (fwd): y_c(t), out = (y_c + ya[tt]) * z2(t). One store, no RMW.
template <int CH, bool G>
__device__ __forceinline__ void phaseC_body(
    const float* __restrict__ u2, const float* __restrict__ u1, const float* __restrict__ uv,
    float* __restrict__ op,
    const f32x2 W0, const f32x2 W1, const f32x2 W2,
    const float w20, const float w21, const float w22,
    const f32x2 (&p2)[8], const f32x2 (&rr2)[8], const float dI,
    const float* __restrict__ cF, const float* __restrict__ cG, int t0) {
    const int t1 = t0 + CH - 1;
    float ya[CH];
    // ---- sweep 1: backward, anti-causal branch + skip into registers ----
    {
        f32x2 g2[8];
        const f32x4* ci = (const f32x4*)cG;
#pragma unroll
        for (int s = 0; s < 4; ++s) {
            const f32x4 q = ci[s];
            g2[2 * s]     = (f32x2){q.x, q.y};
            g2[2 * s + 1] = (f32x2){q.z, q.w};
        }
        f32x2 av4 = {ldc<G>(u1, t1 + 2), ldc<G>(uv, t1 + 2)};
        f32x2 av3 = {ldc<G>(u1, t1 + 1), ldc<G>(uv, t1 + 1)};
        f32x2 av2 = {ldc<G>(u1, t1    ), ldc<G>(uv, t1    )};
        f32x2 av1 = {ldc<G>(u1, t1 - 1), ldc<G>(uv, t1 - 1)};
#pragma unroll
        for (int tt = CH - 1; tt >= 0; --tt) {
            const int t = t0 + tt;
            const f32x2 av0 = {ldc<G>(u1, t - 2), ldc<G>(uv, t - 2)};
            const f32x2 z = __builtin_elementwise_fma(W0, av0 + av4,
                              __builtin_elementwise_fma(W1, av1 + av3, W2 * av2));
            const float x = z.x * z.y;
            const f32x2 xb = {x, x};
#pragma unroll
            for (int s = 0; s < 8; ++s) g2[s] = __builtin_elementwise_fma(p2[s], g2[s], xb);
            f32x2 accA = rr2[0] * g2[0];
            f32x2 accB = rr2[1] * g2[1];
#pragma unroll
            for (int s = 2; s < 8; s += 2) {
                accA = __builtin_elementwise_fma(rr2[s], g2[s], accA);
                accB = __builtin_elementwise_fma(rr2[s + 1], g2[s + 1], accB);
            }
            const f32x2 acc = accA + accB;
            ya[tt] = (acc.x + acc.y) + dI * x;
            av4 = av3; av3 = av2; av2 = av1; av1 = av0;
        }
    }
    // ---- sweep 2: forward, causal branch + combine + gate, single store ----
    {
        f32x2 f2[8];
        const f32x4* ci = (const f32x4*)cF;
#pragma unroll
        for (int s = 0; s < 4; ++s) {
            const f32x4 q = ci[s];
            f2[2 * s]     = (f32x2){q.x, q.y};
            f2[2 * s + 1] = (f32x2){q.z, q.w};
        }
        f32x2 av0 = {ldc<G>(u1, t0 - 2), ldc<G>(uv, t0 - 2)};
        f32x2 av1 = {ldc<G>(u1, t0 - 1), ldc<G>(uv, t0 - 1)};
        f32x2 av2 = {ldc<G>(u1, t0    ), ldc<G>(uv, t0    )};
        f32x2 av3 = {ldc<G>(u1, t0 + 1), ldc<G>(uv, t0 + 1)};
        float e0 = ldc<G>(u2, t0 - 2), e1 = ldc<G>(u2, t0 - 1);
        float e2 = ldc<G>(u2, t0), e3 = ldc<G>(u2, t0 + 1);
#pragma unroll
        for (int tt = 0; tt < CH; ++tt) {
            const int t = t0 + tt;
            const f32x2 av4 = {ldc<G>(u1, t + 2), ldc<G>(uv, t + 2)};
            const float e4 = ldc<G>(u2, t + 2);
            const f32x2 z = __builtin_elementwise_fma(W0, av0 + av4,
                              __builtin_elementwise_fma(W1, av1 + av3, W2 * av2));
            const float z2 = fmaf(w20, e0 + e4, fmaf(w21, e1 + e3, w22 * e2));
            const float x = z.x * z.y;
            const f32x2 xb = {x, x};
#pragma unroll
            for (int s = 0; s < 8; ++s) f2[s] = __builtin_elementwise_fma(p2[s], f2[s], xb);
            f32x2 accA = rr2[0] * f2[0];
            f32x2 accB = rr2[1] * f2[1];
#pragma unroll
            for (int s = 2; s < 8; s += 2) {
                accA = __builtin_elementwise_fma(rr2[s], f2[s], accA);
                accB = __builtin_elementwise_fma(rr2[s + 1], f2[s + 1], accB);
            }
            const f32x2 acc = accA + accB;
            op[(size_t)t * HIDn] = ((acc.x + acc.y) + ya[tt]) * z2;
            av0 = av1; av1 = av2; av2 = av3; av3 = av4;
            e0 = e1; e1 = e2; e2 = e3; e3 = e4;
        }
    }
}

template <int CH>
__global__ __launch_bounds__(64, 3) void hyena_phaseC(
    const float* __restrict__ u, const float* __restrict__ sfw,
    const float* __restrict__ lp, const float* __restrict__ res,
    const float* __restrict__ Dp,
    const float* __restrict__ carryF, const float* __restrict__ carryG,
    float* __restrict__ out) {
    constexpr int NC = Ln / CH;
    const int j = threadIdx.x;
    const int chunk = blockIdx.x;
    const int h = blockIdx.y;
    const int b = blockIdx.z;
    const int c2 = h * 192 + j;       // x2 (gate) column
    const int c1 = c2 + 64;           // x1 column
    const int cv = c2 + 128;          // v column
    const int i = h * 64 + j;
    const int gch = b * HIDn + i;
    const int t0 = chunk * CH;

    const float* u2 = u + (size_t)b * Ln * THIDn + c2;
    const float* u1 = u + (size_t)b * Ln * THIDn + c1;
    const float* uv = u + (size_t)b * Ln * THIDn + cv;
    float* op = out + (size_t)b * Ln * HIDn + i;
    const float w20 = sfw[c2 * 3 + 0], w21 = sfw[c2 * 3 + 1], w22 = 2.0f * sfw[c2 * 3 + 2];
    const f32x2 W0 = {sfw[c1 * 3 + 0], sfw[cv * 3 + 0]};
    const f32x2 W1 = {sfw[c1 * 3 + 1], sfw[cv * 3 + 1]};
    const f32x2 W2 = {2.0f * sfw[c1 * 3 + 2], 2.0f * sfw[cv * 3 + 2]};

    f32x2 p2[8], rr2[8];
#pragma unroll
    for (int s = 0; s < 8; ++s) {
        p2[s]  = (f32x2){expf(lp[2 * s]), expf(lp[2 * s + 1])};
        rr2[s] = (f32x2){res[2 * s], res[2 * s + 1]};  // uniform -> SGPR
    }
    const float dI = Dp[i];
    const size_t cbase = ((size_t)chunk * (Bn * HIDn) + gch) * 16;

    if (chunk >= 1 && chunk <= NC - 2)
        phaseC_body<CH, false>(u2, u1, uv, op, W0, W1, W2, w20, w21, w22,
                               p2, rr2, dI, carryF + cbase, carryG + cbase, t0);
    else
        phaseC_body<CH, true>(u2, u1, uv, op, W0, W1, W2, w20, w21, w22,
                              p2, rr2, dI, carryF + cbase, carryG + cbase, t0);
}

template <int CH>
static void run_all(const float* u, const float* sfw, const float* lp,
                    const float* res, const float* Dp, float* out,
                    void* ws, hipStream_t stream) {
    constexpr int NC = Ln / CH;
    float* carryF = (float*)ws;
    float* carryG = carryF + (size_t)NC * (Bn * HIDn) * 16;
    dim3 grid(NC, HEADSn, Bn);
    hipLaunchKernelGGL((hyena_phaseA<CH>), grid, dim3(64), 0, stream,
                       u, sfw, lp, carryF, carryG);
    hipLaunchKernelGGL((hyena_phaseB<CH>), dim3(256), dim3(256), 0, stream,
                       lp, carryF, carryG);
    hipLaunchKernelGGL((hyena_phaseC<CH>), grid, dim3(64), 0, stream,
                       u, sfw, lp, res, Dp, carryF, carryG, out);
}

extern "C" void kernel_launch(void* const* d_in, const int* in_sizes, int n_in,
                              void* d_out, int out_size, void* d_ws, size_t ws_size,
                              hipStream_t stream) {
    const float* u   = (const float*)d_in[0];  // (B, L, 3*HID) fp32
    const float* sfw = (const float*)d_in[1];  // (3*HID, 1, 3)
    const float* lp  = (const float*)d_in[2];  // (1, 16, 1)
    const float* res = (const float*)d_in[3];  // (1, 16)
    const float* Dp  = (const float*)d_in[4];  // (HID,)
    float* out = (float*)d_out;                // (B, L, HID) fp32

    // carry workspace: NC * 2048 channels * 32 states * 4 B = 2^31/CH bytes
    const size_t need64 = ((size_t)1 << 31) / 64;  // 33.5 MB at CH=64
    if (ws_size >= need64)            run_all<64>(u, sfw, lp, res, Dp, out, d_ws, stream);
    else if (ws_size >= need64 / 2)   run_all<128>(u, sfw, lp, res, Dp, out, d_ws, stream);
    else if (ws_size >= need64 / 4)   run_all<256>(u, sfw, lp, res, Dp, out, d_ws, stream);
    else                              run_all<512>(u, sfw, lp, res, Dp, out, d_ws, stream);
}

// Round 3
// 387.940 us; speedup vs baseline: 1.9464x; 1.6975x over previous
//
#include <hip/hip_runtime.h>
#include <cstdint>
#include <cstddef>

// HyenaCascade on MI355X — 3-phase chunked bidirectional 16-state scan.
// R4: R1 traffic structure (CH=64, fwd-store + bwd-RMW phaseC; merged
//     single-sweep phaseA; unchanged phaseB) + two latency fixes:
//     (1) explicit register double-buffered load pipeline (named buffers,
//         alternated by paired calls -> all indices static, no scratch),
//     (2) 4-wave workgroups at SAME CH=64 (same cache footprint as R1,
//         lifts the ~12.8 waves/CU workgroup cap to the grid's 16).
//     R3 lesson: ya[64] register array spilled (VGPR=84, WRITE +170MB).
//     R2 lesson: more waves via CH=32 blew L3 (FETCH 217->724MB).

#define Bn 2
#define Ln 8192
#define HIDn 1024
#define HEADSn 16
#define STATEn 16
#define THIDn 3072  // 3*HID

typedef __attribute__((ext_vector_type(2))) float f32x2;
typedef __attribute__((ext_vector_type(4))) float f32x4;

#define EFMA __builtin_elementwise_fma

// load u[b, t, c] given base = &u[b,0,c]; zero outside [0,L) when G
template <bool G>
__device__ __forceinline__ float ldc(const float* __restrict__ base, int t) {
    if constexpr (G) return ((unsigned)t < (unsigned)Ln) ? base[(size_t)t * THIDn] : 0.0f;
    else return base[(size_t)t * THIDn];
}

// ---------------- Phase A: per-chunk local finals, ONE sweep, pipelined ------
// fwd final: f = p*f + x.  bwd final: g = sum_tt p^tt x(t0+tt) via running wq.
template <int CH, bool G>
__device__ __forceinline__ void phaseA_body(
    const float* __restrict__ u1, const float* __restrict__ uv,
    const f32x2 W0, const f32x2 W1, const f32x2 W2,
    const f32x2 (&p2)[8], int t0,
    float* __restrict__ cF, float* __restrict__ cG) {
    constexpr int QB = 4, NB = CH / QB;
    f32x2 f2[8], g2[8], wq[8];
#pragma unroll
    for (int s = 0; s < 8; ++s) {
        f2[s] = (f32x2){0.0f, 0.0f};
        g2[s] = (f32x2){0.0f, 0.0f};
        wq[s] = (f32x2){1.0f, 1.0f};
    }
    f32x2 av0 = {ldc<G>(u1, t0 - 2), ldc<G>(uv, t0 - 2)};
    f32x2 av1 = {ldc<G>(u1, t0 - 1), ldc<G>(uv, t0 - 1)};
    f32x2 av2 = {ldc<G>(u1, t0    ), ldc<G>(uv, t0    )};
    f32x2 av3 = {ldc<G>(u1, t0 + 1), ldc<G>(uv, t0 + 1)};
    f32x2 bufA[QB], bufB[QB];
#pragma unroll
    for (int q = 0; q < QB; ++q)
        bufA[q] = (f32x2){ldc<G>(u1, t0 + 2 + q), ldc<G>(uv, t0 + 2 + q)};

    auto blk = [&](f32x2 (&cur)[QB], f32x2 (&nxt)[QB], int kb) {
        if (kb + 1 < NB) {  // issue next block's loads BEFORE computing current
            const int tb = t0 + 2 + QB * (kb + 1);
#pragma unroll
            for (int q = 0; q < QB; ++q)
                nxt[q] = (f32x2){ldc<G>(u1, tb + q), ldc<G>(uv, tb + q)};
        }
#pragma unroll
        for (int q = 0; q < QB; ++q) {
            const f32x2 av4 = cur[q];
            const f32x2 z = EFMA(W0, av0 + av4, EFMA(W1, av1 + av3, W2 * av2));
            const float x = z.x * z.y;
            const f32x2 xb = {x, x};
#pragma unroll
            for (int s = 0; s < 8; ++s) {
                f2[s] = EFMA(p2[s], f2[s], xb);
                g2[s] = EFMA(wq[s], xb, g2[s]);
                wq[s] = wq[s] * p2[s];
            }
            av0 = av1; av1 = av2; av2 = av3; av3 = av4;
        }
    };
    for (int kp = 0; kp < NB / 2; ++kp) {  // runtime loop, static buffer roles
        blk(bufA, bufB, 2 * kp);
        blk(bufB, bufA, 2 * kp + 1);
    }
    f32x4* oF = (f32x4*)cF;
    f32x4* oG = (f32x4*)cG;
#pragma unroll
    for (int s = 0; s < 4; ++s) {
        oF[s] = (f32x4){f2[2 * s].x, f2[2 * s].y, f2[2 * s + 1].x, f2[2 * s + 1].y};
        oG[s] = (f32x4){g2[2 * s].x, g2[2 * s].y, g2[2 * s + 1].x, g2[2 * s + 1].y};
    }
}

template <int CH>
__global__ __launch_bounds__(256, 4) void hyena_phaseA(
    const float* __restrict__ u, const float* __restrict__ sfw,
    const float* __restrict__ lp,
    float* __restrict__ carryF, float* __restrict__ carryG) {
    constexpr int NC = Ln / CH;
    const int lane = threadIdx.x & 63;
    const int chunk = (blockIdx.x << 2) + (threadIdx.x >> 6);  // 4 chunks/WG
    const int h = blockIdx.y;
    const int b = blockIdx.z;
    const int c1 = h * 192 + 64 + lane;  // x1 column in u
    const int cv = c1 + 64;              // v column
    const int t0 = chunk * CH;

    const float* u1 = u + (size_t)b * Ln * THIDn + c1;
    const float* uv = u + (size_t)b * Ln * THIDn + cv;
    const f32x2 W0 = {sfw[c1 * 3 + 0], sfw[cv * 3 + 0]};
    const f32x2 W1 = {sfw[c1 * 3 + 1], sfw[cv * 3 + 1]};
    const f32x2 W2 = {2.0f * sfw[c1 * 3 + 2], 2.0f * sfw[cv * 3 + 2]};
    f32x2 p2[8];
#pragma unroll
    for (int s = 0; s < 8; ++s) p2[s] = (f32x2){expf(lp[2 * s]), expf(lp[2 * s + 1])};

    const int gch = b * HIDn + h * 64 + lane;
    const size_t cbase = ((size_t)chunk * (Bn * HIDn) + gch) * 16;  // chunk-major

    if (chunk >= 1 && chunk <= NC - 2)
        phaseA_body<CH, false>(u1, uv, W0, W1, W2, p2, t0, carryF + cbase, carryG + cbase);
    else
        phaseA_body<CH, true>(u1, uv, W0, W1, W2, p2, t0, carryF + cbase, carryG + cbase);
}

// ---------------- Phase B: carry combine across chunks (in-place) ----------------
template <int CH>
__global__ __launch_bounds__(256) void hyena_phaseB(
    const float* __restrict__ lp,
    float* __restrict__ carryF, float* __restrict__ carryG) {
    constexpr int NC = Ln / CH;
    constexpr int UB = 16;  // batched loads (NC % UB == 0 for all CH used)
    const int dir = blockIdx.x >> 7;                          // blocks 0..127 fwd, 128..255 bwd
    const int ht = ((blockIdx.x & 127) << 8) + threadIdx.x;   // 0..32767
    const int s = ht & 15;
    const int gch = ht >> 4;                                  // 0..2047
    const float pCH = expf(lp[s] * (float)CH);
    float c = 0.0f;
    if (dir == 0) {
        for (int k0 = 0; k0 < NC; k0 += UB) {
            float loc[UB];
#pragma unroll
            for (int q = 0; q < UB; ++q)
                loc[q] = carryF[((size_t)(k0 + q) * (Bn * HIDn) + gch) * 16 + s];
#pragma unroll
            for (int q = 0; q < UB; ++q) {
                carryF[((size_t)(k0 + q) * (Bn * HIDn) + gch) * 16 + s] = c;
                c = fmaf(pCH, c, loc[q]);
            }
        }
    } else {
        for (int k0 = NC - UB; k0 >= 0; k0 -= UB) {
            float loc[UB];
#pragma unroll
            for (int q = UB - 1; q >= 0; --q)
                loc[q] = carryG[((size_t)(k0 + q) * (Bn * HIDn) + gch) * 16 + s];
#pragma unroll
            for (int q = UB - 1; q >= 0; --q) {
                carryG[((size_t)(k0 + q) * (Bn * HIDn) + gch) * 16 + s] = c;
                c = fmaf(pCH, c, loc[q]);
            }
        }
    }
}

// ---------------- Phase C: seeded scans + gating, pipelined ----------------
// fwd sweep writes causal y_c to out; bwd sweep does same-thread RMW:
// out = (y_c + y_a + D*x) * x2. All addresses lane-private -> no sync needed.
template <int CH, bool G>
__device__ __forceinline__ void phaseC_body(
    const float* __restrict__ u2, const float* __restrict__ u1, const float* __restrict__ uv,
    float* __restrict__ op,
    const f32x2 W0, const f32x2 W1, const f32x2 W2,
    const float w20, const float w21, const float w22,
    const f32x2 (&p2)[8], const f32x2 (&rr2)[8], const float dI,
    const float* __restrict__ cF, const float* __restrict__ cG, int t0) {
    const int t1 = t0 + CH - 1;
    // ---- fwd: causal branch, y_c -> out ----
    {
        constexpr int QB = 8, NB = CH / QB;
        f32x2 f2[8];
        const f32x4* ci = (const f32x4*)cF;
#pragma unroll
        for (int s = 0; s < 4; ++s) {
            const f32x4 q = ci[s];
            f2[2 * s]     = (f32x2){q.x, q.y};
            f2[2 * s + 1] = (f32x2){q.z, q.w};
        }
        f32x2 av0 = {ldc<G>(u1, t0 - 2), ldc<G>(uv, t0 - 2)};
        f32x2 av1 = {ldc<G>(u1, t0 - 1), ldc<G>(uv, t0 - 1)};
        f32x2 av2 = {ldc<G>(u1, t0    ), ldc<G>(uv, t0    )};
        f32x2 av3 = {ldc<G>(u1, t0 + 1), ldc<G>(uv, t0 + 1)};
        f32x2 bufA[QB], bufB[QB];
#pragma unroll
        for (int q = 0; q < QB; ++q)
            bufA[q] = (f32x2){ldc<G>(u1, t0 + 2 + q), ldc<G>(uv, t0 + 2 + q)};

        auto blk = [&](f32x2 (&cur)[QB], f32x2 (&nxt)[QB], int kb) {
            if (kb + 1 < NB) {
                const int tb = t0 + 2 + QB * (kb + 1);
#pragma unroll
                for (int q = 0; q < QB; ++q)
                    nxt[q] = (f32x2){ldc<G>(u1, tb + q), ldc<G>(uv, tb + q)};
            }
#pragma unroll
            for (int q = 0; q < QB; ++q) {
                const int t = t0 + QB * kb + q;
                const f32x2 av4 = cur[q];
                const f32x2 z = EFMA(W0, av0 + av4, EFMA(W1, av1 + av3, W2 * av2));
                const float x = z.x * z.y;
                const f32x2 xb = {x, x};
#pragma unroll
                for (int s = 0; s < 8; ++s) f2[s] = EFMA(p2[s], f2[s], xb);
                f32x2 accA = rr2[0] * f2[0];
                f32x2 accB = rr2[1] * f2[1];
#pragma unroll
                for (int s = 2; s < 8; s += 2) {
                    accA = EFMA(rr2[s], f2[s], accA);
                    accB = EFMA(rr2[s + 1], f2[s + 1], accB);
                }
                const f32x2 acc = accA + accB;
                op[(size_t)t * HIDn] = acc.x + acc.y;
                av0 = av1; av1 = av2; av2 = av3; av3 = av4;
            }
        };
        for (int kp = 0; kp < NB / 2; ++kp) {
            blk(bufA, bufB, 2 * kp);
            blk(bufB, bufA, 2 * kp + 1);
        }
    }
    // ---- bwd: anti-causal branch + skip + gate, RMW out ----
    {
        constexpr int QB = 4, NB = CH / QB;
        f32x2 g2[8];
        const f32x4* ci = (const f32x4*)cG;
#pragma unroll
        for (int s = 0; s < 4; ++s) {
            const f32x4 q = ci[s];
            g2[2 * s]     = (f32x2){q.x, q.y};
            g2[2 * s + 1] = (f32x2){q.z, q.w};
        }
        f32x2 av4 = {ldc<G>(u1, t1 + 2), ldc<G>(uv, t1 + 2)};
        f32x2 av3 = {ldc<G>(u1, t1 + 1), ldc<G>(uv, t1 + 1)};
        f32x2 av2 = {ldc<G>(u1, t1    ), ldc<G>(uv, t1    )};
        f32x2 av1 = {ldc<G>(u1, t1 - 1), ldc<G>(uv, t1 - 1)};
        float e4 = ldc<G>(u2, t1 + 2), e3 = ldc<G>(u2, t1 + 1);
        float e2 = ldc<G>(u2, t1), e1 = ldc<G>(u2, t1 - 1);
        f32x2 avA[QB], avB[QB];
        float eA[QB], eB[QB], ycA[QB], ycB[QB];
#pragma unroll
        for (int q = 0; q < QB; ++q) {  // block 0: tt = CH-1-q
            const int t = t0 + CH - 1 - q;
            avA[q] = (f32x2){ldc<G>(u1, t - 2), ldc<G>(uv, t - 2)};
            eA[q]  = ldc<G>(u2, t - 2);
            ycA[q] = op[(size_t)t * HIDn];
        }

        auto blk = [&](f32x2 (&cav)[QB], float (&ce)[QB], float (&cyc)[QB],
                       f32x2 (&nav)[QB], float (&ne)[QB], float (&nyc)[QB], int kb) {
            if (kb + 1 < NB) {
#pragma unroll
                for (int q = 0; q < QB; ++q) {
                    const int t = t0 + CH - 1 - QB * (kb + 1) - q;
                    nav[q] = (f32x2){ldc<G>(u1, t - 2), ldc<G>(uv, t - 2)};
                    ne[q]  = ldc<G>(u2, t - 2);
                    nyc[q] = op[(size_t)t * HIDn];
                }
            }
#pragma unroll
            for (int q = 0; q < QB; ++q) {
                const int t = t0 + CH - 1 - QB * kb - q;
                const f32x2 av0 = cav[q];
                const float e0 = ce[q];
                const float yc = cyc[q];
                const f32x2 z = EFMA(W0, av0 + av4, EFMA(W1, av1 + av3, W2 * av2));
                const float z2 = fmaf(w20, e0 + e4, fmaf(w21, e1 + e3, w22 * e2));
                const float x = z.x * z.y;
                const f32x2 xb = {x, x};
#pragma unroll
                for (int s = 0; s < 8; ++s) g2[s] = EFMA(p2[s], g2[s], xb);
                f32x2 accA = rr2[0] * g2[0];
                f32x2 accB = rr2[1] * g2[1];
#pragma unroll
                for (int s = 2; s < 8; s += 2) {
                    accA = EFMA(rr2[s], g2[s], accA);
                    accB = EFMA(rr2[s + 1], g2[s + 1], accB);
                }
                const f32x2 acc = accA + accB;
                const float ya = acc.x + acc.y;
                op[(size_t)t * HIDn] = (yc + ya + dI * x) * z2;
                av4 = av3; av3 = av2; av2 = av1; av1 = av0;
                e4 = e3; e3 = e2; e2 = e1; e1 = e0;
            }
        };
        for (int kp = 0; kp < NB / 2; ++kp) {
            blk(avA, eA, ycA, avB, eB, ycB, 2 * kp);
            blk(avB, eB, ycB, avA, eA, ycA, 2 * kp + 1);
        }
    }
}

template <int CH>
__global__ __launch_bounds__(256, 4) void hyena_phaseC(
    const float* __restrict__ u, const float* __restrict__ sfw,
    const float* __restrict__ lp, const float* __restrict__ res,
    const float* __restrict__ Dp,
    const float* __restrict__ carryF, const float* __restrict__ carryG,
    float* __restrict__ out) {
    constexpr int NC = Ln / CH;
    const int lane = threadIdx.x & 63;
    const int chunk = (blockIdx.x << 2) + (threadIdx.x >> 6);  // 4 chunks/WG
    const int h = blockIdx.y;
    const int b = blockIdx.z;
    const int c2 = h * 192 + lane;    // x2 (gate) column
    const int c1 = c2 + 64;           // x1 column
    const int cv = c2 + 128;          // v column
    const int i = h * 64 + lane;
    const int gch = b * HIDn + i;
    const int t0 = chunk * CH;

    const float* u2 = u + (size_t)b * Ln * THIDn + c2;
    const float* u1 = u + (size_t)b * Ln * THIDn + c1;
    const float* uv = u + (size_t)b * Ln * THIDn + cv;
    float* op = out + (size_t)b * Ln * HIDn + i;
    const float w20 = sfw[c2 * 3 + 0], w21 = sfw[c2 * 3 + 1], w22 = 2.0f * sfw[c2 * 3 + 2];
    const f32x2 W0 = {sfw[c1 * 3 + 0], sfw[cv * 3 + 0]};
    const f32x2 W1 = {sfw[c1 * 3 + 1], sfw[cv * 3 + 1]};
    const f32x2 W2 = {2.0f * sfw[c1 * 3 + 2], 2.0f * sfw[cv * 3 + 2]};

    f32x2 p2[8], rr2[8];
#pragma unroll
    for (int s = 0; s < 8; ++s) {
        p2[s]  = (f32x2){expf(lp[2 * s]), expf(lp[2 * s + 1])};
        rr2[s] = (f32x2){res[2 * s], res[2 * s + 1]};
    }
    const float dI = Dp[i];
    const size_t cbase = ((size_t)chunk * (Bn * HIDn) + gch) * 16;

    if (chunk >= 1 && chunk <= NC - 2)
        phaseC_body<CH, false>(u2, u1, uv, op, W0, W1, W2, w20, w21, w22,
                               p2, rr2, dI, carryF + cbase, carryG + cbase, t0);
    else
        phaseC_body<CH, true>(u2, u1, uv, op, W0, W1, W2, w20, w21, w22,
                              p2, rr2, dI, carryF + cbase, carryG + cbase, t0);
}

template <int CH>
static void run_all(const float* u, const float* sfw, const float* lp,
                    const float* res, const float* Dp, float* out,
                    void* ws, hipStream_t stream) {
    constexpr int NC = Ln / CH;
    static_assert(NC % 4 == 0, "4 chunks per workgroup");
    float* carryF = (float*)ws;
    float* carryG = carryF + (size_t)NC * (Bn * HIDn) * 16;
    dim3 grid(NC / 4, HEADSn, Bn);
    hipLaunchKernelGGL((hyena_phaseA<CH>), grid, dim3(256), 0, stream,
                       u, sfw, lp, carryF, carryG);
    hipLaunchKernelGGL((hyena_phaseB<CH>), dim3(256), dim3(256), 0, stream,
                       lp, carryF, carryG);
    hipLaunchKernelGGL((hyena_phaseC<CH>), grid, dim3(256), 0, stream,
                       u, sfw, lp, res, Dp, carryF, carryG, out);
}

extern "C" void kernel_launch(void* const* d_in, const int* in_sizes, int n_in,
                              void* d_out, int out_size, void* d_ws, size_t ws_size,
                              hipStream_t stream) {
    const float* u   = (const float*)d_in[0];  // (B, L, 3*HID) fp32
    const float* sfw = (const float*)d_in[1];  // (3*HID, 1, 3)
    const float* lp  = (const float*)d_in[2];  // (1, 16, 1)
    const float* res = (const float*)d_in[3];  // (1, 16)
    const float* Dp  = (const float*)d_in[4];  // (HID,)
    float* out = (float*)d_out;                // (B, L, HID) fp32

    // carry workspace: NC * 2048 channels * 32 states * 4 B = 2^31/CH bytes
    const size_t need64 = ((size_t)1 << 31) / 64;  // 33.5 MB at CH=64
    if (ws_size >= need64)            run_all<64>(u, sfw, lp, res, Dp, out, d_ws, stream);
    else if (ws_size >= need64 / 2)   run_all<128>(u, sfw, lp, res, Dp, out, d_ws, stream);
    else if (ws_size >= need64 / 4)   run_all<256>(u, sfw, lp, res, Dp, out, d_ws, stream);
    else                              run_all<512>(u, sfw, lp, res, Dp, out, d_ws, stream);
}